// Round 1
// baseline (301.380 us; speedup 1.0000x reference)
//
#include <hip/hip_runtime.h>
#include <hip/hip_bf16.h>

#define BATCH 16
#define NV    20000
#define FIN   64
#define NCOUT 64
#define NK    16
#define TOTROWS  (BATCH * NV)      // 320000
#define NTILES   (TOTROWS / 16)    // 20000 row-tiles of 16

typedef __attribute__((ext_vector_type(8))) short bf16x8;   // 8 bf16 (4 VGPRs)
typedef __attribute__((ext_vector_type(4))) float f32x4;    // MFMA acc

__device__ __forceinline__ short f2b(float f) {
    __hip_bfloat16 h = __float2bfloat16(f);   // RTNE
    return __builtin_bit_cast(short, h);
}

// ---------------------------------------------------------------------------
// Pass A: one x-sweep, MFMA 16x16x32 bf16.
//   p[row][c]   = x[row]@Wx[:,c] + bias[c]      -> out  (fp32)
//   z[row][c]   = x[row]@(Wn[:,c]/16)           -> ws   (bf16)
// Wave handles a 16-row tile x 128 cols = 8 col-tiles x 2 k-halves = 16 MFMA.
// B-frags (weights) built ONCE into 64 VGPRs -- round-3 lesson: the compiler
// refuses to keep fp32 weight *arrays* resident across a loop (VGPR_Count=84
// with 128 floats "in registers" => it was re-streaming 32 KB/row through L1).
// MFMA frags are hot operands of the loop body; they stay resident.
// ---------------------------------------------------------------------------
__global__ __launch_bounds__(256, 3) void convnet_gemm(
    const float* __restrict__ x,      // (320000, 64)
    const float* __restrict__ Wx,     // (64, 64)
    const float* __restrict__ Wn,     // (64, 64)
    const float* __restrict__ bias,   // (64)
    __hip_bfloat16* __restrict__ z,   // (320000, 64) bf16  [ws]
    float* __restrict__ out)          // (320000, 64) fp32  (gets p)
{
    const int lane = threadIdx.x & 63;
    const int m    = lane & 15;    // row-in-tile (A), col-in-tile (B, C/D)
    const int quad = lane >> 4;    // 0..3

    // B fragments: bf[t][h], t 0..3 = Wx (-> p), t 4..7 = Wn/16 (-> z).
    // Layout (verified m91/gemm_bt): frag[j] = W[k][n], n = lane&15,
    // k = 32*h + quad*8 + j.
    bf16x8 bf[8][2];
#pragma unroll
    for (int t = 0; t < 8; ++t) {
        const float* W = (t < 4) ? Wx : Wn;
        const float scale = (t < 4) ? 1.0f : (1.0f / 16.0f);
        const int c = (t & 3) * 16 + m;
#pragma unroll
        for (int h = 0; h < 2; ++h) {
            bf16x8 fr;
#pragma unroll
            for (int j = 0; j < 8; ++j) {
                const int f = 32 * h + quad * 8 + j;
                fr[j] = f2b(W[f * NCOUT + c] * scale);
            }
            bf[t][h] = fr;
        }
    }
    float bias_q[4];
#pragma unroll
    for (int t = 0; t < 4; ++t) bias_q[t] = bias[t * 16 + m];

    const int nwaves = (gridDim.x * blockDim.x) >> 6;   // 3072
    const int gw = (blockIdx.x * blockDim.x + threadIdx.x) >> 6;

    for (int rt = gw; rt < NTILES; rt += nwaves) {
        const int rtu = __builtin_amdgcn_readfirstlane(rt);
        const float* xt = x + (size_t)rtu * (16 * FIN);

        // A fragments: frag[j] = x[row = m][k = 32h + quad*8 + j] of the tile.
        bf16x8 af[2];
#pragma unroll
        for (int h = 0; h < 2; ++h) {
            const float4* p4 =
                (const float4*)(xt + (size_t)m * FIN + 32 * h + quad * 8);
            const float4 lo = p4[0];
            const float4 hi = p4[1];
            bf16x8 fr;
            fr[0] = f2b(lo.x); fr[1] = f2b(lo.y);
            fr[2] = f2b(lo.z); fr[3] = f2b(lo.w);
            fr[4] = f2b(hi.x); fr[5] = f2b(hi.y);
            fr[6] = f2b(hi.z); fr[7] = f2b(hi.w);
            af[h] = fr;
        }

        f32x4 acc[8];
#pragma unroll
        for (int t = 0; t < 8; ++t) acc[t] = (f32x4){0.f, 0.f, 0.f, 0.f};
#pragma unroll
        for (int h = 0; h < 2; ++h)
#pragma unroll
            for (int t = 0; t < 8; ++t)
                acc[t] = __builtin_amdgcn_mfma_f32_16x16x32_bf16(
                    af[h], bf[t][h], acc[t], 0, 0, 0);

        // C/D layout (verified m89/m91): value r of tile t sits at
        // row = quad*4 + r, col = (t&3)*16 + m.
        const size_t rbase = (size_t)rtu * 16 + quad * 4;
#pragma unroll
        for (int r = 0; r < 4; ++r) {
            const size_t orow = (rbase + r) * NCOUT;
#pragma unroll
            for (int t = 0; t < 4; ++t)
                out[orow + t * 16 + m] = acc[t][r] + bias_q[t];
#pragma unroll
            for (int t = 4; t < 8; ++t)
                z[orow + (t - 4) * 16 + m] = __float2bfloat16(acc[t][r]);
        }
    }
}

// ---------------------------------------------------------------------------
// Pass B: out[b,v,:] += sum_k z[b, nbr[v,k]-1, :]  (idx==0 = zero pad).
// Pure gather-add: no matmul VALU. bf16 z window/batch = 2.56 MB < 4 MiB L2;
// 1024 blocks @ (256,4) = exactly 4 blocks/CU -> ALL blocks co-resident, and
// blockIdx%8 pins each XCD to its two batches (one live window per L2).
// ---------------------------------------------------------------------------
__global__ __launch_bounds__(256, 4) void convnet_gather(
    const int* __restrict__ nbr,           // (20000, 16), values in [0, V]
    const __hip_bfloat16* __restrict__ z,  // (320000, 64) bf16
    float* __restrict__ out)               // (320000, 64) fp32, has p already
{
    const int lane = threadIdx.x & 63;
    const int xcd  = blockIdx.x & 7;
    const int bi   = blockIdx.x >> 3;                       // 0..127
    const int wl   = (bi * blockDim.x + threadIdx.x) >> 6;  // 0..511
    const int rows_per_xcd = 2 * NV;
    const int base = xcd * rows_per_xcd;

    for (int r = wl; r < rows_per_xcd; r += 512) {
        const int rowu = __builtin_amdgcn_readfirstlane(base + r);
        const int in_b1 = (r >= NV) ? 1 : 0;
        const int v = r - in_b1 * NV;

        const int* nbrow = nbr + (size_t)v * NK;
        const size_t zbase = (size_t)(rowu - v) * NCOUT;    // b*NV*64

        float g0 = 0.f, g1 = 0.f, g2 = 0.f, g3 = 0.f;
#pragma unroll
        for (int k = 0; k < NK; ++k) {
            const int idx = nbrow[k];                       // uniform s_load
            int sel = idx - 1;
            sel = sel < 0 ? 0 : sel;                        // clamp pad
            const float val =
                __bfloat162float(z[zbase + (size_t)sel * NCOUT + lane]);
            const float mval = idx ? val : 0.0f;
            if ((k & 3) == 0) g0 += mval;
            else if ((k & 3) == 1) g1 += mval;
            else if ((k & 3) == 2) g2 += mval;
            else g3 += mval;
        }

        const size_t o = (size_t)rowu * NCOUT + lane;
        out[o] += (g0 + g1) + (g2 + g3);
    }
}

extern "C" void kernel_launch(void* const* d_in, const int* in_sizes, int n_in,
                              void* d_out, int out_size, void* d_ws, size_t ws_size,
                              hipStream_t stream) {
    const float* x    = (const float*)d_in[0];
    const float* Wx   = (const float*)d_in[1];
    const float* Wn   = (const float*)d_in[2];
    const float* bias = (const float*)d_in[3];
    const int*   nbr  = (const int*)d_in[4];
    float* out = (float*)d_out;

    __hip_bfloat16* z = (__hip_bfloat16*)d_ws;   // 40.96 MB (proven fits ws)

    hipLaunchKernelGGL(convnet_gemm, dim3(768), dim3(256), 0, stream,
                       x, Wx, Wn, bias, z, out);
    hipLaunchKernelGGL(convnet_gather, dim3(1024), dim3(256), 0, stream,
                       nbr, z, out);
}

// Round 2
// 225.138 us; speedup vs baseline: 1.3386x; 1.3386x over previous
//
#include <hip/hip_runtime.h>
#include <hip/hip_bf16.h>

#define BATCH 16
#define NV    20000
#define FIN   64
#define NCOUT 64
#define NK    16
#define TOTROWS  (BATCH * NV)      // 320000
#define NTILES   (TOTROWS / 16)    // 20000 row-tiles of 16

typedef __attribute__((ext_vector_type(8))) short bf16x8;   // 8 bf16 (4 VGPRs)
typedef __attribute__((ext_vector_type(4))) float f32x4;    // MFMA acc
typedef __attribute__((ext_vector_type(4))) unsigned short u16x4;

__device__ __forceinline__ short f2b(float f) {
    __hip_bfloat16 h = __float2bfloat16(f);   // RTNE
    return __builtin_bit_cast(short, h);
}

// ---------------------------------------------------------------------------
// Pass A: one x-sweep, MFMA 16x16x32 bf16.
//   p[row][c] = x[row]@Wx[:,c] + bias[c]  -> out (fp32)
//   z[row][c] = x[row]@(Wn[:,c]/16)       -> ws  (bf16)
// ROUND-1 CHANGE: col-tile t now covers global cols {4m+t} (permuted B-frag
// load) so a lane's 4 t-values per row are CONSECUTIVE cols ->
//   out: 1 global_store_dwordx4 per row   (was 4 dword stores)
//   z:   1 global_store_dwordx2 per row   (was 4 ushort stores)
// 32 -> 8 store instrs/tile kills the vmcnt WAR serialization on acc reuse.
// Also: software-prefetch next tile's raw x float4s before the epilogue so
// the HBM load latency hides under MFMA+stores of the current tile.
// ---------------------------------------------------------------------------
__global__ __launch_bounds__(256, 3) void convnet_gemm(
    const float* __restrict__ x,      // (320000, 64)
    const float* __restrict__ Wx,     // (64, 64)
    const float* __restrict__ Wn,     // (64, 64)
    const float* __restrict__ bias,   // (64)
    __hip_bfloat16* __restrict__ z,   // (320000, 64) bf16  [ws]
    float* __restrict__ out)          // (320000, 64) fp32  (gets p)
{
    const int lane = threadIdx.x & 63;
    const int m    = lane & 15;    // row-in-tile (A), col-in-tile (B, C/D)
    const int quad = lane >> 4;    // 0..3

    // B fragments: bf[t][h], t 0..3 = Wx (-> p), t 4..7 = Wn/16 (-> z).
    // frag[j] = W[k][colmap], k = 32*h + quad*8 + j, colmap = 4*m + (t&3).
    bf16x8 bf[8][2];
#pragma unroll
    for (int t = 0; t < 8; ++t) {
        const float* W = (t < 4) ? Wx : Wn;
        const float scale = (t < 4) ? 1.0f : (1.0f / 16.0f);
        const int c = 4 * m + (t & 3);
#pragma unroll
        for (int h = 0; h < 2; ++h) {
            bf16x8 fr;
#pragma unroll
            for (int j = 0; j < 8; ++j) {
                const int f = 32 * h + quad * 8 + j;
                fr[j] = f2b(W[f * NCOUT + c] * scale);
            }
            bf[t][h] = fr;
        }
    }
    float bias_q[4];
#pragma unroll
    for (int t = 0; t < 4; ++t) bias_q[t] = bias[4 * m + t];

    const int nwaves = (gridDim.x * blockDim.x) >> 6;   // 3072
    const int gw = (blockIdx.x * blockDim.x + threadIdx.x) >> 6;

    int rt = __builtin_amdgcn_readfirstlane(gw);
    // prefetch raw x for first tile (elements 32h + quad*8 + 0..7 of row m)
    const float* xt0 = x + (size_t)rt * (16 * FIN) + (size_t)m * FIN + quad * 8;
    float4 La0 = ((const float4*)xt0)[0];
    float4 La1 = ((const float4*)xt0)[1];
    float4 Lb0 = ((const float4*)(xt0 + 32))[0];
    float4 Lb1 = ((const float4*)(xt0 + 32))[1];

    for (;;) {
        // convert current raw x -> A fragments (waits vmcnt on L*)
        bf16x8 af0, af1;
        af0[0] = f2b(La0.x); af0[1] = f2b(La0.y); af0[2] = f2b(La0.z); af0[3] = f2b(La0.w);
        af0[4] = f2b(La1.x); af0[5] = f2b(La1.y); af0[6] = f2b(La1.z); af0[7] = f2b(La1.w);
        af1[0] = f2b(Lb0.x); af1[1] = f2b(Lb0.y); af1[2] = f2b(Lb0.z); af1[3] = f2b(Lb0.w);
        af1[4] = f2b(Lb1.x); af1[5] = f2b(Lb1.y); af1[6] = f2b(Lb1.z); af1[7] = f2b(Lb1.w);

        // issue next tile's loads NOW (hide under MFMA + epilogue)
        const int rtn = rt + nwaves;
        const bool more = rtn < NTILES;
        float4 Na0, Na1, Nb0, Nb1;
        if (more) {
            const float* xn = x + (size_t)rtn * (16 * FIN) + (size_t)m * FIN + quad * 8;
            Na0 = ((const float4*)xn)[0];
            Na1 = ((const float4*)xn)[1];
            Nb0 = ((const float4*)(xn + 32))[0];
            Nb1 = ((const float4*)(xn + 32))[1];
        }

        f32x4 acc[8];
#pragma unroll
        for (int t = 0; t < 8; ++t) acc[t] = (f32x4){0.f, 0.f, 0.f, 0.f};
#pragma unroll
        for (int t = 0; t < 8; ++t)
            acc[t] = __builtin_amdgcn_mfma_f32_16x16x32_bf16(af0, bf[t][0], acc[t], 0, 0, 0);
#pragma unroll
        for (int t = 0; t < 8; ++t)
            acc[t] = __builtin_amdgcn_mfma_f32_16x16x32_bf16(af1, bf[t][1], acc[t], 0, 0, 0);

        // C/D: value r of tile t sits at row quad*4 + r, col 4m + t.
        const size_t rbase = (size_t)rt * 16 + quad * 4;
#pragma unroll
        for (int r = 0; r < 4; ++r) {
            const size_t orow = (rbase + r) * NCOUT + 4 * m;
            float4 o;
            o.x = acc[0][r] + bias_q[0];
            o.y = acc[1][r] + bias_q[1];
            o.z = acc[2][r] + bias_q[2];
            o.w = acc[3][r] + bias_q[3];
            *(float4*)(out + orow) = o;
            u16x4 zz;
            zz.x = (unsigned short)f2b(acc[4][r]);
            zz.y = (unsigned short)f2b(acc[5][r]);
            zz.z = (unsigned short)f2b(acc[6][r]);
            zz.w = (unsigned short)f2b(acc[7][r]);
            *(u16x4*)(z + orow) = zz;
        }

        if (!more) break;
        rt = __builtin_amdgcn_readfirstlane(rtn);
        La0 = Na0; La1 = Na1; Lb0 = Nb0; Lb1 = Nb1;
    }
}

// ---------------------------------------------------------------------------
// Pass B: out[b,v,:] += sum_k z[b, nbr[v,k]-1, :]  (idx==0 = zero pad).
// ROUND-1 RESTRUCTURE: wave handles 4 consecutive rows (4 | NV so a group
// never crosses a batch). lane = (s = lane>>4 sub-row, c = lane&15 col-grp).
// Gathers are dwordx2 (4 bf16, 8B/lane -> 512B/instr) instead of ushort
// (2B/lane): 4x fewer gather instrs and ~4x less VALU/row. All bases are
// wave-scalar (readfirstlane g) so per-k math is 1 lshl_add + mask + 4 adds.
// bf16->f32 by shift/mask (exact), no cvt instructions.
// XCD pinning kept: blockIdx&7 -> 2 batches per XCD, z window 2.56MB/batch,
// waves sweep batch A then batch B (one live window per L2).
// ---------------------------------------------------------------------------
__global__ __launch_bounds__(256, 6) void convnet_gather(
    const int* __restrict__ nbr,           // (20000, 16), values in [0, V]
    const __hip_bfloat16* __restrict__ z,  // (320000, 64) bf16
    float* __restrict__ out)               // (320000, 64) fp32, has p already
{
    const int lane = threadIdx.x & 63;
    const int s    = lane >> 4;            // sub-row 0..3
    const int c    = lane & 15;            // col group (4 cols)
    const int xcd  = blockIdx.x & 7;
    const int bi   = blockIdx.x >> 3;                        // 0..191
    const int wl   = bi * (256 >> 6) + (threadIdx.x >> 6);   // 0..767
    const int WPX  = (gridDim.x >> 3) * (256 >> 6);          // 768 waves/xcd

    const int nvoff = s * (NK * 4);        // byte offset to sub-row's nbr row
    const int zcol  = c * 8;               // byte col offset (4 bf16)
    const int GROUPS = (2 * NV) / 4;       // 10000 groups per xcd

    for (int g = wl; g < GROUPS; g += WPX) {
        const int gu = __builtin_amdgcn_readfirstlane(g);
        const int bl = (gu >= NV / 4) ? 1 : 0;
        const int b  = 2 * xcd + bl;
        const int v0 = gu * 4 - bl * NV;
        const int row0 = b * NV + v0;      // global out row of sub-row 0

        // neighbor indices for this lane's sub-row: 16 dword loads, one 64B
        // line per sub-row, imm offsets -- no per-k address VALU.
        const int* nb = (const int*)((const char*)nbr + (size_t)v0 * (NK * 4) + nvoff);
        int id[NK];
#pragma unroll
        for (int k = 0; k < NK; ++k) id[k] = nb[k];

        const char* zb = (const char*)z + (size_t)b * NV * 128;  // batch base
        float a0 = 0.f, a1 = 0.f, a2 = 0.f, a3 = 0.f;
#pragma unroll
        for (int k = 0; k < NK; ++k) {
            const int idx = id[k];
            int sel = idx - 1;
            sel = sel < 0 ? 0 : sel;       // clamp pad (row 0 read, masked)
            const uint2 d = *(const uint2*)(zb + (size_t)(unsigned)(sel * 128 + zcol));
            const unsigned dx = idx ? d.x : 0u;
            const unsigned dy = idx ? d.y : 0u;
            a0 += __builtin_bit_cast(float, dx << 16);
            a1 += __builtin_bit_cast(float, dx & 0xFFFF0000u);
            a2 += __builtin_bit_cast(float, dy << 16);
            a3 += __builtin_bit_cast(float, dy & 0xFFFF0000u);
        }

        float4* o = (float4*)(out + (size_t)(row0 + s) * NCOUT + 4 * c);
        float4 ov = *o;
        ov.x += a0; ov.y += a1; ov.z += a2; ov.w += a3;
        *o = ov;
    }
}

extern "C" void kernel_launch(void* const* d_in, const int* in_sizes, int n_in,
                              void* d_out, int out_size, void* d_ws, size_t ws_size,
                              hipStream_t stream) {
    const float* x    = (const float*)d_in[0];
    const float* Wx   = (const float*)d_in[1];
    const float* Wn   = (const float*)d_in[2];
    const float* bias = (const float*)d_in[3];
    const int*   nbr  = (const int*)d_in[4];
    float* out = (float*)d_out;

    __hip_bfloat16* z = (__hip_bfloat16*)d_ws;   // 40.96 MB (proven fits ws)

    hipLaunchKernelGGL(convnet_gemm, dim3(768), dim3(256), 0, stream,
                       x, Wx, Wn, bias, z, out);
    hipLaunchKernelGGL(convnet_gather, dim3(1536), dim3(256), 0, stream,
                       nbr, z, out);
}